// Round 1
// baseline (42619.574 us; speedup 1.0000x reference)
//
#include <hip/hip_runtime.h>
#include <hip/hip_bf16.h>
#include <cstdint>
#include <cstddef>

#define D 2048
#define P 1024
#define G 8192   // 4*D
#define NB 16    // batch
#define T0 512
#define T1 511   // after conv

typedef unsigned short u16;
typedef unsigned int u32;

typedef __attribute__((ext_vector_type(8))) __bf16 bf16x8;
typedef __attribute__((ext_vector_type(4))) float f32x4;

__device__ __forceinline__ u16 f2bf(float f){
  u32 u = __float_as_uint(f);
  u32 r = (u + 0x7fffu + ((u >> 16) & 1u)) >> 16;
  return (u16)r;
}
__device__ __forceinline__ float bf2f(u16 h){
  return __uint_as_float(((u32)h) << 16);
}

// ---------------------------------------------------------------------------
// Generic bf16 MFMA GEMM: C[M,N] = A[M,K] * B[K,N] (+bias), B given as Bt[N,K].
// A row r base = r*lda + (r/agrp)*aextra  (agrp/aextra implement the conv's
// overlapping-row gather; normal GEMMs pass agrp=1<<30, aextra=0).
// ---------------------------------------------------------------------------
__global__ __launch_bounds__(256) void gemm_bf16(
    int M, int N, int K,
    const u16* __restrict__ A, int lda, int agrp, int aextra,
    const u16* __restrict__ Bt,
    u16* __restrict__ C, int ldc,
    const float* __restrict__ bias)
{
  __shared__ u16 As[128][40];
  __shared__ u16 Bs[128][40];
  const int tid = threadIdx.x;
  const int l = tid & 63;
  const int w = tid >> 6;
  const int wm = w >> 1, wn = w & 1;
  const int bm = blockIdx.y, bn = blockIdx.x;
  const int col = l & 15, q = l >> 4;
  f32x4 acc[4][4] = {};

  for (int k0 = 0; k0 < K; k0 += 32){
#pragma unroll
    for (int i = 0; i < 2; ++i){
      int ch = tid + 256*i;
      int row = ch >> 2;
      int kc = (ch & 3) * 8;
      int rg = bm*128 + row;
      uint4 av = make_uint4(0u,0u,0u,0u);
      if (rg < M){
        size_t base = (size_t)rg*lda + (size_t)(rg/agrp)*aextra + k0 + kc;
        av = *(const uint4*)(A + base);
      }
      *(uint4*)&As[row][kc] = av;
      int ng = bn*128 + row;
      *(uint4*)&Bs[row][kc] = *(const uint4*)(Bt + (size_t)ng*K + k0 + kc);
    }
    __syncthreads();
    bf16x8 af[4], bfr[4];
#pragma unroll
    for (int i = 0; i < 4; ++i)
      af[i] = *(const bf16x8*)&As[wm*64 + i*16 + col][q*8];
#pragma unroll
    for (int j = 0; j < 4; ++j)
      bfr[j] = *(const bf16x8*)&Bs[wn*64 + j*16 + col][q*8];
#pragma unroll
    for (int i = 0; i < 4; ++i)
#pragma unroll
      for (int j = 0; j < 4; ++j)
        acc[i][j] = __builtin_amdgcn_mfma_f32_16x16x32_bf16(af[i], bfr[j], acc[i][j], 0, 0, 0);
    __syncthreads();
  }
#pragma unroll
  for (int i = 0; i < 4; ++i){
#pragma unroll
    for (int j = 0; j < 4; ++j){
#pragma unroll
      for (int r = 0; r < 4; ++r){
        int m = bm*128 + wm*64 + i*16 + q*4 + r;
        int n = bn*128 + wn*64 + j*16 + col;
        if (m < M){
          float v = acc[i][j][r];
          if (bias) v += bias[n];
          C[(size_t)m*ldc + n] = f2bf(v);
        }
      }
    }
  }
}

// ---------------------------------------------------------------------------
// Transpose-cast: src fp32 (R,C) row-major (leading dim src_ld) -> dst bf16 (C,R)
// ---------------------------------------------------------------------------
__global__ __launch_bounds__(256) void tcast_kernel(
    const float* __restrict__ src, int src_ld, int R, int C, u16* __restrict__ dst)
{
  __shared__ float tile[32][33];
  int bx = blockIdx.x;   // along C
  int by = blockIdx.y;   // along R
  int tx = threadIdx.x & 31;
  int ty = threadIdx.x >> 5;  // 0..7
  int c0 = bx*32, r0 = by*32;
#pragma unroll
  for (int i = 0; i < 32; i += 8)
    tile[ty + i][tx] = src[(size_t)(r0 + ty + i)*src_ld + c0 + tx];
  __syncthreads();
#pragma unroll
  for (int i = 0; i < 32; i += 8)
    dst[(size_t)(c0 + ty + i)*R + r0 + tx] = f2bf(tile[tx][ty + i]);
}

__global__ void cast_kernel(const float* __restrict__ src, u16* __restrict__ dst, size_t n){
  size_t i = (size_t)blockIdx.x*blockDim.x + threadIdx.x;
  size_t stride = (size_t)gridDim.x*blockDim.x;
  for (; i < n; i += stride) dst[i] = f2bf(src[i]);
}

__global__ void h0_from_state(const float* __restrict__ state_h, u16* __restrict__ h0b){
  int i = blockIdx.x*blockDim.x + threadIdx.x; // 16384
  int b = i >> 10, p = i & 1023;
  h0b[i] = f2bf(state_h[(size_t)b*D + p]);
}

__global__ void h0_from_h(const u16* __restrict__ Hb, int Tprev, u16* __restrict__ h0b){
  int i = blockIdx.x*blockDim.x + threadIdx.x;
  int b = i >> 10, p = i & 1023;
  h0b[i] = Hb[((size_t)b*Tprev + Tprev - 1)*P + p];
}

__global__ void out_h_kernel(const u16* __restrict__ Hb, float* __restrict__ outh){
  int i = blockIdx.x*blockDim.x + threadIdx.x;
  int b = i >> 10, p = i & 1023;
  outh[i] = bf2f(Hb[((size_t)b*T1 + T1 - 1)*P + p]);
}

// ---------------------------------------------------------------------------
// LayerNorm over last dim (P=1024); one block per row.
// ---------------------------------------------------------------------------
__global__ __launch_bounds__(256) void ln_kernel(
    const u16* __restrict__ Hb,
    const float* __restrict__ gamma, const float* __restrict__ beta,
    u16* __restrict__ outb, float* __restrict__ outf)
{
  int r = blockIdx.x;
  int tid = threadIdx.x;
  const u16* x = Hb + (size_t)r*P;
  float v[4], s = 0.f, s2 = 0.f;
#pragma unroll
  for (int i = 0; i < 4; ++i){
    float f = bf2f(x[tid + i*256]);
    v[i] = f; s += f; s2 += f*f;
  }
#pragma unroll
  for (int off = 32; off > 0; off >>= 1){
    s  += __shfl_down(s, off);
    s2 += __shfl_down(s2, off);
  }
  __shared__ float sm[8];
  int wv = tid >> 6;
  if ((tid & 63) == 0){ sm[wv] = s; sm[4 + wv] = s2; }
  __syncthreads();
  if (tid == 0){
    float S  = sm[0]+sm[1]+sm[2]+sm[3];
    float S2 = sm[4]+sm[5]+sm[6]+sm[7];
    float mean = S * (1.f/1024.f);
    float var  = S2 * (1.f/1024.f) - mean*mean;
    sm[0] = mean;
    sm[1] = rsqrtf(var + 1e-3f);
  }
  __syncthreads();
  float mean = sm[0], rstd = sm[1];
#pragma unroll
  for (int i = 0; i < 4; ++i){
    int c = tid + i*256;
    float o = (v[i] - mean)*rstd*gamma[c] + beta[c];
    if (outb) outb[(size_t)r*P + c] = f2bf(o);
    else      outf[(size_t)r*P + c] = o;
  }
}

// ---------------------------------------------------------------------------
// Persistent recurrence kernel. 256 blocks x 256 threads (1 block/CU, all
// co-resident). Block blk owns d-dims [8*blk, 8*blk+8) => 32 gate columns,
// packed into two 16-wide MFMA N-tiles: tile0=(i|j), tile1=(f|o).
// Whp slice held in registers (B-fragments). Per step: u_{t-1} @ Whp_slice
// via 32 MFMAs/wave (K split across 4 waves), cross-wave reduce in LDS,
// elementwise cell update (c in registers), write u_t, global software barrier.
// t=0 uses precomputed xg_0 + h0@Wh (no MFMA).
// ---------------------------------------------------------------------------
__global__ __launch_bounds__(256) void rec_kernel(
    const u16* __restrict__ Whp,   // (G, D) n-major: Whp[n][d] = (proj@Wh)[d][n]
    const u16* __restrict__ XG,    // (NB*T, G) bf16, row = b*T+t
    const u16* __restrict__ hwh0,  // (NB, G) bf16 : h0 @ Wh
    const float* __restrict__ c_in,   // (NB, D)
    float* __restrict__ c_out,        // (NB, D)
    float* __restrict__ c_out2,       // nullable (d_out c section)
    u16* __restrict__ U,              // (NB*T, D) bf16
    int T,
    u32* __restrict__ bar)            // >= T counters, zeroed
{
  const int blk = blockIdx.x;      // 0..255
  const int tid = threadIdx.x;
  const int l = tid & 63;
  const int w = tid >> 6;
  const int col = l & 15, q = l >> 4;
  const int d0 = blk * 8;

  const int n_t0 = (col < 8) ? (d0 + col) : (D + d0 + col - 8);        // i | j
  const int n_t1 = (col < 8) ? (2*D + d0 + col) : (3*D + d0 + col - 8); // f | o

  bf16x8 wf0[16], wf1[16];
#pragma unroll
  for (int i = 0; i < 16; ++i){
    int kb = w*16 + i;
    wf0[i] = *(const bf16x8*)(Whp + (size_t)n_t0*D + kb*32 + q*8);
    wf1[i] = *(const bf16x8*)(Whp + (size_t)n_t1*D + kb*32 + q*8);
  }

  __shared__ float red[4][2][64][4];

  const int b_ew = tid >> 3;   // used only when tid < 128 => 0..15
  const int dd_ew = tid & 7;
  float c_reg = 0.f;
  if (tid < 128) c_reg = c_in[(size_t)b_ew*D + d0 + dd_ew];

  for (int t = 0; t < T; ++t){
    float gi = 0.f, gj = 0.f, gf = 0.f, go = 0.f;
    if (t > 0){
      f32x4 a0 = {0.f,0.f,0.f,0.f}, a1 = {0.f,0.f,0.f,0.f};
      const size_t arow = ((size_t)(l & 15) * T + (t-1)) * D;
#pragma unroll
      for (int i = 0; i < 16; ++i){
        int kb = w*16 + i;
        bf16x8 av = *(const bf16x8*)(U + arow + kb*32 + q*8);
        a0 = __builtin_amdgcn_mfma_f32_16x16x32_bf16(av, wf0[i], a0, 0, 0, 0);
        a1 = __builtin_amdgcn_mfma_f32_16x16x32_bf16(av, wf1[i], a1, 0, 0, 0);
      }
      *(f32x4*)&red[w][0][l][0] = a0;
      *(f32x4*)&red[w][1][l][0] = a1;
      __syncthreads();
      if (tid < 128){
        int lane_a = ((b_ew >> 2) << 4) + dd_ew;  // C-layout: col=lane&15, row=(lane>>4)*4+reg
        int lane_b = lane_a + 8;
        int rr = b_ew & 3;
#pragma unroll
        for (int w2 = 0; w2 < 4; ++w2){
          gi += red[w2][0][lane_a][rr];
          gj += red[w2][0][lane_b][rr];
          gf += red[w2][1][lane_a][rr];
          go += red[w2][1][lane_b][rr];
        }
      }
    }
    if (tid < 128){
      size_t row = (size_t)b_ew*T + t;
      const u16* xg = XG + row*(size_t)G;
      float xi = bf2f(xg[d0 + dd_ew]);
      float xj = bf2f(xg[D + d0 + dd_ew]);
      float xf = bf2f(xg[2*D + d0 + dd_ew]);
      float xo = bf2f(xg[3*D + d0 + dd_ew]);
      if (t == 0){
        const u16* hh = hwh0 + (size_t)b_ew*G;
        gi = xi + bf2f(hh[d0 + dd_ew]);
        gj = xj + bf2f(hh[D + d0 + dd_ew]);
        gf = xf + bf2f(hh[2*D + d0 + dd_ew]);
        go = xo + bf2f(hh[3*D + d0 + dd_ew]);
      } else {
        gi += xi; gj += xj; gf += xf; go += xo;
      }
      float ff = 1.f/(1.f + expf(-(gf + 1.f)));
      float ii = 1.f/(1.f + expf(-gi));
      float oo = 1.f/(1.f + expf(-go));
      c_reg = ff*c_reg + ii*tanhf(gj);
      float u = oo*tanhf(c_reg);
      U[row*(size_t)D + d0 + dd_ew] = f2bf(u);
    }
    // ---- software grid barrier (256 co-resident blocks) ----
    __syncthreads();
    if (tid == 0){
      __threadfence();  // release: flush u_t writes (agent scope wb)
      __hip_atomic_fetch_add(&bar[t], 1u, __ATOMIC_RELAXED, __HIP_MEMORY_SCOPE_AGENT);
      while (__hip_atomic_load(&bar[t], __ATOMIC_RELAXED, __HIP_MEMORY_SCOPE_AGENT) < 256u){
        __builtin_amdgcn_s_sleep(1);
      }
      __threadfence();  // acquire: invalidate before reading other blocks' u_t
    }
    __syncthreads();
  }
  if (tid < 128){
    c_out[(size_t)b_ew*D + d0 + dd_ew] = c_reg;
    if (c_out2) c_out2[(size_t)b_ew*D + d0 + dd_ew] = c_reg;
  }
}

// ---------------------------------------------------------------------------
extern "C" void kernel_launch(void* const* d_in, const int* in_sizes, int n_in,
                              void* d_out, int out_size, void* d_ws, size_t ws_size,
                              hipStream_t stream)
{
  (void)in_sizes; (void)n_in; (void)out_size; (void)ws_size;
  const float* inputs = (const float*)d_in[0];
  const float* state  = (const float*)d_in[1];   // (2, NB, D)
  const float* kernels= (const float*)d_in[2];   // (4, 2P, G)
  const float* biases = (const float*)d_in[3];   // (4, G)
  const float* projs  = (const float*)d_in[4];   // (4, D, P)
  const float* ln_g   = (const float*)d_in[5];
  const float* ln_b   = (const float*)d_in[6];
  const float* conv_w = (const float*)d_in[7];   // (2, P, P)
  const float* conv_b = (const float*)d_in[8];
  float* out = (float*)d_out;

  char* ws = (char*)d_ws;
  size_t off = 0;
  auto alloc = [&](size_t bytes)->char*{
    char* p = ws + off;
    off = (off + bytes + 255) & ~(size_t)255;
    return p;
  };
  u16* Wxb = (u16*)alloc((size_t)G*P*2);        // Wx^T  (G,P)
  u16* Whb = (u16*)alloc((size_t)G*P*2);        // Wh^T  (G,P)
  u16* Pdp = (u16*)alloc((size_t)D*P*2);        // proj  (D,P)
  u16* Ppd = (u16*)alloc((size_t)P*D*2);        // proj^T(P,D)
  u16* Whp = (u16*)alloc((size_t)G*D*2);        // (proj@Wh)^T (G,D)
  u16* Cwb = (u16*)alloc((size_t)P*2*P*2);      // conv_w^T (P, 2P)
  u16* XG  = (u16*)alloc((size_t)NB*T0*G*2);
  u16* U   = (u16*)alloc((size_t)NB*T0*D*2);
  u16* Xa  = (u16*)alloc((size_t)NB*T0*P*2);
  u16* Xb  = (u16*)alloc((size_t)NB*T0*P*2);
  u16* Hb  = (u16*)alloc((size_t)NB*T0*P*2);
  u16* h0b = (u16*)alloc((size_t)NB*P*2);
  u16* hwh0= (u16*)alloc((size_t)NB*G*2);
  float* c_carry = (float*)alloc((size_t)NB*D*4);
  u32* bar = (u32*)alloc(4096);

  float* out_main = out;                          // (NB, 511, P)
  float* out_c = out + (size_t)NB*T1*P;           // (NB, D)
  float* out_h = out_c + (size_t)NB*D;            // (NB, P)

  const int BIG = 1 << 30;

  // one-time: conv weight transpose-cast, input cast
  tcast_kernel<<<dim3(P/32, 2*P/32), 256, 0, stream>>>(conv_w, P, 2*P, P, Cwb);
  cast_kernel<<<4096, 256, 0, stream>>>(inputs, Xa, (size_t)NB*T0*P);

  const int Tcur[4] = {512, 512, 511, 511};
  for (int l = 0; l < 4; ++l){
    const int T = Tcur[l];
    const int Mrows = NB*T;
    const u16* Xin = (l == 0) ? Xa : ((l == 3) ? Xa : Xb);  // l0:Xa, l1:Xb, l2:Xb, l3:Xa

    const float* kl = kernels + (size_t)l*2*P*G;
    // weight casts (JIT per layer)
    tcast_kernel<<<dim3(G/32, P/32), 256, 0, stream>>>(kl, G, P, G, Wxb);
    tcast_kernel<<<dim3(G/32, P/32), 256, 0, stream>>>(kl + (size_t)P*G, G, P, G, Whb);
    cast_kernel<<<2048, 256, 0, stream>>>(projs + (size_t)l*D*P, Pdp, (size_t)D*P);
    tcast_kernel<<<dim3(P/32, D/32), 256, 0, stream>>>(projs + (size_t)l*D*P, P, D, P, Ppd);

    // Whp^T[n][d] = sum_p Wh^T[n][p] * proj[d][p]  -> GEMM M=G, N=D, K=P
    gemm_bf16<<<dim3(D/128, G/128), 256, 0, stream>>>(G, D, P, Whb, P, BIG, 0, Pdp, Whp, D, nullptr);

    // XG = X @ Wx + bias : M=NB*T, N=G, K=P
    gemm_bf16<<<dim3(G/128, (Mrows + 127)/128), 256, 0, stream>>>(
        Mrows, G, P, Xin, P, BIG, 0, Wxb, XG, G, biases + (size_t)l*G);

    // h0 (bf16): layer0 from state[1][:, :P], else last row of previous Hb
    if (l == 0) h0_from_state<<<64, 256, 0, stream>>>(state + (size_t)NB*D, h0b);
    else        h0_from_h<<<64, 256, 0, stream>>>(Hb, Tcur[l-1], h0b);

    // hwh0 = h0 @ Wh : M=NB, N=G, K=P
    gemm_bf16<<<dim3(G/128, 1), 256, 0, stream>>>(NB, G, P, h0b, P, BIG, 0, Whb, hwh0, G, nullptr);

    // recurrence
    hipMemsetAsync(bar, 0, 4096, stream);
    rec_kernel<<<256, 256, 0, stream>>>(
        Whp, XG, hwh0,
        (l == 0) ? state : c_carry, c_carry, (l == 3) ? out_c : nullptr,
        U, T, bar);

    // H = U @ proj : M=NB*T, N=P, K=D
    gemm_bf16<<<dim3(P/128, (Mrows + 127)/128), 256, 0, stream>>>(
        Mrows, P, D, U, D, BIG, 0, Ppd, Hb, P, nullptr);

    if (l == 3) out_h_kernel<<<64, 256, 0, stream>>>(Hb, out_h);

    // LayerNorm: l0 -> Xb, l1 -> Xa (conv input), l2 -> Xa, l3 -> d_out (fp32)
    u16* lnout_b = (l == 0) ? Xb : ((l == 3) ? nullptr : Xa);
    ln_kernel<<<Mrows, 256, 0, stream>>>(Hb, ln_g, ln_b, lnout_b, (l == 3) ? out_main : nullptr);

    if (l == 1){
      // conv over time (VALID, width 2): rows overlap => K=2P read spans
      // LN1 rows (b,t) and (b,t+1), which are contiguous. A base = (r + r/511)*P.
      gemm_bf16<<<dim3(P/128, (NB*T1 + 127)/128), 256, 0, stream>>>(
          NB*T1, P, 2*P, Xa, P, T1, P, Cwb, Xb, P, conv_b);
    }
  }
}

// Round 3
// 25593.323 us; speedup vs baseline: 1.6653x; 1.6653x over previous
//
#include <hip/hip_runtime.h>
#include <hip/hip_bf16.h>
#include <cstdint>
#include <cstddef>

#define D 2048
#define P 1024
#define G 8192   // 4*D
#define NB 16    // batch
#define T0 512
#define T1 511   // after conv

typedef unsigned short u16;
typedef unsigned int u32;
typedef unsigned long long u64;

typedef __attribute__((ext_vector_type(8))) __bf16 bf16x8;
typedef __attribute__((ext_vector_type(4))) float f32x4;

union frag2 { u64 d[2]; bf16x8 f; uint4 u; };

__device__ __forceinline__ u16 f2bf(float f){
  u32 u = __float_as_uint(f);
  u32 r = (u + 0x7fffu + ((u >> 16) & 1u)) >> 16;
  return (u16)r;
}
__device__ __forceinline__ float bf2f(u16 h){
  return __uint_as_float(((u32)h) << 16);
}

// ---------------------------------------------------------------------------
// Generic bf16 MFMA GEMM: C[M,N] = A[M,K] * B[K,N] (+bias), B given as Bt[N,K].
// A row r base = r*lda + (r/agrp)*aextra (conv overlapping-row gather).
// ---------------------------------------------------------------------------
__global__ __launch_bounds__(256) void gemm_bf16(
    int M, int N, int K,
    const u16* __restrict__ A, int lda, int agrp, int aextra,
    const u16* __restrict__ Bt,
    u16* __restrict__ C, int ldc,
    const float* __restrict__ bias)
{
  __shared__ u16 As[128][40];
  __shared__ u16 Bs[128][40];
  const int tid = threadIdx.x;
  const int l = tid & 63;
  const int w = tid >> 6;
  const int wm = w >> 1, wn = w & 1;
  const int bm = blockIdx.y, bn = blockIdx.x;
  const int col = l & 15, q = l >> 4;
  f32x4 acc[4][4] = {};

  for (int k0 = 0; k0 < K; k0 += 32){
#pragma unroll
    for (int i = 0; i < 2; ++i){
      int ch = tid + 256*i;
      int row = ch >> 2;
      int kc = (ch & 3) * 8;
      int rg = bm*128 + row;
      uint4 av = make_uint4(0u,0u,0u,0u);
      if (rg < M){
        size_t base = (size_t)rg*lda + (size_t)(rg/agrp)*aextra + k0 + kc;
        av = *(const uint4*)(A + base);
      }
      *(uint4*)&As[row][kc] = av;
      int ng = bn*128 + row;
      *(uint4*)&Bs[row][kc] = *(const uint4*)(Bt + (size_t)ng*K + k0 + kc);
    }
    __syncthreads();
    bf16x8 af[4], bfr[4];
#pragma unroll
    for (int i = 0; i < 4; ++i)
      af[i] = *(const bf16x8*)&As[wm*64 + i*16 + col][q*8];
#pragma unroll
    for (int j = 0; j < 4; ++j)
      bfr[j] = *(const bf16x8*)&Bs[wn*64 + j*16 + col][q*8];
#pragma unroll
    for (int i = 0; i < 4; ++i)
#pragma unroll
      for (int j = 0; j < 4; ++j)
        acc[i][j] = __builtin_amdgcn_mfma_f32_16x16x32_bf16(af[i], bfr[j], acc[i][j], 0, 0, 0);
    __syncthreads();
  }
#pragma unroll
  for (int i = 0; i < 4; ++i){
#pragma unroll
    for (int j = 0; j < 4; ++j){
#pragma unroll
      for (int r = 0; r < 4; ++r){
        int m = bm*128 + wm*64 + i*16 + q*4 + r;
        int n = bn*128 + wn*64 + j*16 + col;
        if (m < M){
          float v = acc[i][j][r];
          if (bias) v += bias[n];
          C[(size_t)m*ldc + n] = f2bf(v);
        }
      }
    }
  }
}

// ---------------------------------------------------------------------------
__global__ __launch_bounds__(256) void tcast_kernel(
    const float* __restrict__ src, int src_ld, int R, int C, u16* __restrict__ dst)
{
  __shared__ float tile[32][33];
  int bx = blockIdx.x;   // along C
  int by = blockIdx.y;   // along R
  int tx = threadIdx.x & 31;
  int ty = threadIdx.x >> 5;  // 0..7
  int c0 = bx*32, r0 = by*32;
#pragma unroll
  for (int i = 0; i < 32; i += 8)
    tile[ty + i][tx] = src[(size_t)(r0 + ty + i)*src_ld + c0 + tx];
  __syncthreads();
#pragma unroll
  for (int i = 0; i < 32; i += 8)
    dst[(size_t)(c0 + ty + i)*R + r0 + tx] = f2bf(tile[tx][ty + i]);
}

__global__ void cast_kernel(const float* __restrict__ src, u16* __restrict__ dst, size_t n){
  size_t i = (size_t)blockIdx.x*blockDim.x + threadIdx.x;
  size_t stride = (size_t)gridDim.x*blockDim.x;
  for (; i < n; i += stride) dst[i] = f2bf(src[i]);
}

__global__ void h0_from_state(const float* __restrict__ state_h, u16* __restrict__ h0b){
  int i = blockIdx.x*blockDim.x + threadIdx.x; // 16384
  int b = i >> 10, p = i & 1023;
  h0b[i] = f2bf(state_h[(size_t)b*D + p]);
}

__global__ void h0_from_h(const u16* __restrict__ Hb, int Tprev, u16* __restrict__ h0b){
  int i = blockIdx.x*blockDim.x + threadIdx.x;
  int b = i >> 10, p = i & 1023;
  h0b[i] = Hb[((size_t)b*Tprev + Tprev - 1)*P + p];
}

__global__ void out_h_kernel(const u16* __restrict__ Hb, float* __restrict__ outh){
  int i = blockIdx.x*blockDim.x + threadIdx.x;
  int b = i >> 10, p = i & 1023;
  outh[i] = bf2f(Hb[((size_t)b*T1 + T1 - 1)*P + p]);
}

// ---------------------------------------------------------------------------
__global__ __launch_bounds__(256) void ln_kernel(
    const u16* __restrict__ Hb,
    const float* __restrict__ gamma, const float* __restrict__ beta,
    u16* __restrict__ outb, float* __restrict__ outf)
{
  int r = blockIdx.x;
  int tid = threadIdx.x;
  const u16* x = Hb + (size_t)r*P;
  float v[4], s = 0.f, s2 = 0.f;
#pragma unroll
  for (int i = 0; i < 4; ++i){
    float f = bf2f(x[tid + i*256]);
    v[i] = f; s += f; s2 += f*f;
  }
#pragma unroll
  for (int off = 32; off > 0; off >>= 1){
    s  += __shfl_down(s, off);
    s2 += __shfl_down(s2, off);
  }
  __shared__ float sm[8];
  int wv = tid >> 6;
  if ((tid & 63) == 0){ sm[wv] = s; sm[4 + wv] = s2; }
  __syncthreads();
  if (tid == 0){
    float S  = sm[0]+sm[1]+sm[2]+sm[3];
    float S2 = sm[4]+sm[5]+sm[6]+sm[7];
    float mean = S * (1.f/1024.f);
    float var  = S2 * (1.f/1024.f) - mean*mean;
    sm[0] = mean;
    sm[1] = rsqrtf(var + 1e-3f);
  }
  __syncthreads();
  float mean = sm[0], rstd = sm[1];
#pragma unroll
  for (int i = 0; i < 4; ++i){
    int c = tid + i*256;
    float o = (v[i] - mean)*rstd*gamma[c] + beta[c];
    if (outb) outb[(size_t)r*P + c] = f2bf(o);
    else      outf[(size_t)r*P + c] = o;
  }
}

// ---------------------------------------------------------------------------
// Persistent recurrence kernel, fence-free LLC-coherent communication.
// 256 blocks x 256 threads, 1 block/CU (forced by 139 KB LDS). Block owns
// 8 d-dims = 32 gate cols (two 16-wide MFMA N-tiles: (i|j), (f|o)).
// Whp slice lives in LDS in MFMA-fragment order (conflict-free ds_read_b128,
// each lane reads back its own 16B slot). Cross-block data path (no fences,
// no wbl2/inv — everything meets at the LLC):
//   U writes : relaxed agent-scope atomic u32 stores (-> LLC)
//   U reads  : relaxed agent-scope atomic u64 loads  (-> LLC)
//   barrier  : per-step flag vector; wave0 drains stores (s_waitcnt vmcnt(0))
//              then lane0 sets flags[t][blk]; wave1 polls all 256 flags;
//              __syncthreads releases the block.
// ---------------------------------------------------------------------------
__global__ __launch_bounds__(256) void rec_kernel(
    const u16* __restrict__ Whp,   // (G, D): Whp[n][d] = (proj@Wh)[d][n]
    const u16* __restrict__ XG,    // (NB*T, G) bf16
    const u16* __restrict__ hwh0,  // (NB, G) bf16 : h0 @ Wh
    const float* __restrict__ c_in,
    float* __restrict__ c_out,
    float* __restrict__ c_out2,    // nullable (d_out c section)
    u16* __restrict__ U,           // (NB*T, D) bf16 — LLC-coherent access only
    int T,
    u32* __restrict__ flags)       // [T][256], zeroed before launch
{
  const int blk = blockIdx.x;
  const int tid = threadIdx.x;
  const int l = tid & 63;
  const int w = tid >> 6;
  const int col = l & 15, q = l >> 4;
  const int d0 = blk * 8;

  const int n_t0 = (col < 8) ? (d0 + col) : (D + d0 + col - 8);         // i | j
  const int n_t1 = (col < 8) ? (2*D + d0 + col) : (3*D + d0 + col - 8); // f | o

  // Whp fragments in LDS, fragment-major: [wave][tile][frag][lane*8 .. +8)
  __shared__ u16 WhpS[4][2][16][512];   // 128 KB
  __shared__ float red[4][2][64][4];    // 8 KB

#pragma unroll
  for (int i = 0; i < 16; ++i){
    uint4 v0 = *(const uint4*)(Whp + (size_t)n_t0*D + (w*16 + i)*32 + q*8);
    uint4 v1 = *(const uint4*)(Whp + (size_t)n_t1*D + (w*16 + i)*32 + q*8);
    *(uint4*)&WhpS[w][0][i][l*8] = v0;
    *(uint4*)&WhpS[w][1][i][l*8] = v1;
  }
  __syncthreads();

  // elementwise mapping: 64 threads (wave 0), 2 dims per thread
  const int b_ew = tid >> 2;        // 0..15 (batch)
  const int dd0  = (tid & 3) * 2;   // dim pair within the block's 8 dims
  float2 c_reg = make_float2(0.f, 0.f);
  if (tid < 64)
    c_reg = *(const float2*)(c_in + (size_t)b_ew*D + d0 + dd0);

  const u64 EXPECT = 0x0000000100000001ULL;

  for (int t = 0; t < T; ++t){
    float gi0=0.f,gi1=0.f,gj0=0.f,gj1=0.f,gf0=0.f,gf1=0.f,go0=0.f,go1=0.f;
    if (t > 0){
      // wave 1: poll previous step's flags (16 lanes x 16 flags each)
      if (w == 1){
        const u64* fp = (const u64*)(flags + (size_t)(t-1)*256 + (l & 15)*16);
        for (;;){
          bool ok = true;
          if (l < 16){
            u64 a = __hip_atomic_load(fp + 0, __ATOMIC_RELAXED, __HIP_MEMORY_SCOPE_AGENT);
            u64 b = __hip_atomic_load(fp + 1, __ATOMIC_RELAXED, __HIP_MEMORY_SCOPE_AGENT);
            u64 c = __hip_atomic_load(fp + 2, __ATOMIC_RELAXED, __HIP_MEMORY_SCOPE_AGENT);
            u64 d = __hip_atomic_load(fp + 3, __ATOMIC_RELAXED, __HIP_MEMORY_SCOPE_AGENT);
            ok = (a == EXPECT) & (b == EXPECT) & (c == EXPECT) & (d == EXPECT);
          }
          if (__all(ok)) break;
          __builtin_amdgcn_s_sleep(1);
        }
      }
      __syncthreads();   // release: U_{t-1} globally visible (wave1 verified)

      // A fragments of u_{t-1} from LLC (agent-scope relaxed u64 loads)
      const u16* abase = U + ((size_t)(l & 15)*T + (t-1))*D + (size_t)w*512 + q*8;
      frag2 av[16];
#pragma unroll
      for (int i = 0; i < 16; ++i){
        const u64* p = (const u64*)(abase + i*32);
        av[i].d[0] = __hip_atomic_load(p + 0, __ATOMIC_RELAXED, __HIP_MEMORY_SCOPE_AGENT);
        av[i].d[1] = __hip_atomic_load(p + 1, __ATOMIC_RELAXED, __HIP_MEMORY_SCOPE_AGENT);
      }
      f32x4 a0 = {0.f,0.f,0.f,0.f}, a1 = {0.f,0.f,0.f,0.f};
#pragma unroll
      for (int i = 0; i < 16; ++i){
        bf16x8 wf0 = *(const bf16x8*)&WhpS[w][0][i][l*8];
        bf16x8 wf1 = *(const bf16x8*)&WhpS[w][1][i][l*8];
        a0 = __builtin_amdgcn_mfma_f32_16x16x32_bf16(av[i].f, wf0, a0, 0, 0, 0);
        a1 = __builtin_amdgcn_mfma_f32_16x16x32_bf16(av[i].f, wf1, a1, 0, 0, 0);
      }
      *(f32x4*)&red[w][0][l][0] = a0;
      *(f32x4*)&red[w][1][l][0] = a1;
    }
    __syncthreads();   // red complete (t>0); plain rendezvous at t==0

    if (tid < 64){
      if (t > 0){
        int lane0 = ((b_ew >> 2) << 4) + dd0;   // C-layout: col=lane&15, row=(lane>>4)*4+reg
        int rr = b_ew & 3;
#pragma unroll
        for (int w2 = 0; w2 < 4; ++w2){
          gi0 += red[w2][0][lane0  ][rr]; gi1 += red[w2][0][lane0+1][rr];
          gj0 += red[w2][0][lane0+8][rr]; gj1 += red[w2][0][lane0+9][rr];
          gf0 += red[w2][1][lane0  ][rr]; gf1 += red[w2][1][lane0+1][rr];
          go0 += red[w2][1][lane0+8][rr]; go1 += red[w2][1][lane0+9][rr];
        }
      }
      size_t row = (size_t)b_ew*T + t;
      const u16* xg = XG + row*(size_t)G + d0 + dd0;
      float xi0 = bf2f(xg[0]),   xi1 = bf2f(xg[1]);
      float xj0 = bf2f(xg[D]),   xj1 = bf2f(xg[D+1]);
      float xf0 = bf2f(xg[2*D]), xf1 = bf2f(xg[2*D+1]);
      float xo0 = bf2f(xg[3*D]), xo1 = bf2f(xg[3*D+1]);
      if (t == 0){
        const u16* hh = hwh0 + (size_t)b_ew*G + d0 + dd0;
        gi0 = xi0 + bf2f(hh[0]);   gi1 = xi1 + bf2f(hh[1]);
        gj0 = xj0 + bf2f(hh[D]);   gj1 = xj1 + bf2f(hh[D+1]);
        gf0 = xf0 + bf2f(hh[2*D]); gf1 = xf1 + bf2f(hh[2*D+1]);
        go0 = xo0 + bf2f(hh[3*D]); go1 = xo1 + bf2f(hh[3*D+1]);
      } else {
        gi0 += xi0; gi1 += xi1; gj0 += xj0; gj1 += xj1;
        gf0 += xf0; gf1 += xf1; go0 += xo0; go1 += xo1;
      }
      float ff0 = 1.f/(1.f + expf(-(gf0 + 1.f)));
      float ff1 = 1.f/(1.f + expf(-(gf1 + 1.f)));
      float ii0 = 1.f/(1.f + expf(-gi0));
      float ii1 = 1.f/(1.f + expf(-gi1));
      float oo0 = 1.f/(1.f + expf(-go0));
      float oo1 = 1.f/(1.f + expf(-go1));
      c_reg.x = ff0*c_reg.x + ii0*tanhf(gj0);
      c_reg.y = ff1*c_reg.y + ii1*tanhf(gj1);
      float u0 = oo0*tanhf(c_reg.x);
      float u1 = oo1*tanhf(c_reg.y);
      u32 up = (u32)f2bf(u0) | ((u32)f2bf(u1) << 16);
      __hip_atomic_store((u32*)(U + row*(size_t)D + d0 + dd0), up,
                         __ATOMIC_RELAXED, __HIP_MEMORY_SCOPE_AGENT);
      // drain wave-0's U stores to the LLC, then publish the flag
      asm volatile("s_waitcnt vmcnt(0)" ::: "memory");
      if (tid == 0)
        __hip_atomic_store(&flags[(size_t)t*256 + blk], 1u,
                           __ATOMIC_RELAXED, __HIP_MEMORY_SCOPE_AGENT);
    }
    // waves 1-3 proceed straight to polling step t+1
  }
  if (tid < 64){
    *(float2*)(c_out + (size_t)b_ew*D + d0 + dd0) = c_reg;
    if (c_out2) *(float2*)(c_out2 + (size_t)b_ew*D + d0 + dd0) = c_reg;
  }
}

// ---------------------------------------------------------------------------
extern "C" void kernel_launch(void* const* d_in, const int* in_sizes, int n_in,
                              void* d_out, int out_size, void* d_ws, size_t ws_size,
                              hipStream_t stream)
{
  (void)in_sizes; (void)n_in; (void)out_size; (void)ws_size;
  const float* inputs = (const float*)d_in[0];
  const float* state  = (const float*)d_in[1];   // (2, NB, D)
  const float* kernels= (const float*)d_in[2];   // (4, 2P, G)
  const float* biases = (const float*)d_in[3];   // (4, G)
  const float* projs  = (const float*)d_in[4];   // (4, D, P)
  const float* ln_g   = (const float*)d_in[5];
  const float* ln_b   = (const float*)d_in[6];
  const float* conv_w = (const float*)d_in[7];   // (2, P, P)
  const float* conv_b = (const float*)d_in[8];
  float* out = (float*)d_out;

  char* ws = (char*)d_ws;
  size_t off = 0;
  auto alloc = [&](size_t bytes)->char*{
    char* p = ws + off;
    off = (off + bytes + 255) & ~(size_t)255;
    return p;
  };
  u16* Wxb = (u16*)alloc((size_t)G*P*2);        // Wx^T  (G,P)
  u16* Whb = (u16*)alloc((size_t)G*P*2);        // Wh^T  (G,P)
  u16* Pdp = (u16*)alloc((size_t)D*P*2);        // proj  (D,P)
  u16* Ppd = (u16*)alloc((size_t)P*D*2);        // proj^T(P,D)
  u16* Whp = (u16*)alloc((size_t)G*D*2);        // (proj@Wh)^T (G,D)
  u16* Cwb = (u16*)alloc((size_t)P*2*P*2);      // conv_w^T (P, 2P)
  u16* XG  = (u16*)alloc((size_t)NB*T0*G*2);
  u16* U   = (u16*)alloc((size_t)NB*T0*D*2);
  u16* Xa  = (u16*)alloc((size_t)NB*T0*P*2);
  u16* Xb  = (u16*)alloc((size_t)NB*T0*P*2);
  u16* Hb  = (u16*)alloc((size_t)NB*T0*P*2);
  u16* h0b = (u16*)alloc((size_t)NB*P*2);
  u16* hwh0= (u16*)alloc((size_t)NB*G*2);
  float* c_carry = (float*)alloc((size_t)NB*D*4);
  u32* flags = (u32*)alloc((size_t)T0*256*4);   // 512 KB step flags

  float* out_main = out;                          // (NB, 511, P)
  float* out_c = out + (size_t)NB*T1*P;           // (NB, D)
  float* out_h = out_c + (size_t)NB*D;            // (NB, P)

  const int BIG = 1 << 30;

  // one-time: conv weight transpose-cast, input cast
  tcast_kernel<<<dim3(P/32, 2*P/32), 256, 0, stream>>>(conv_w, P, 2*P, P, Cwb);
  cast_kernel<<<4096, 256, 0, stream>>>(inputs, Xa, (size_t)NB*T0*P);

  const int Tcur[4] = {512, 512, 511, 511};
  for (int l = 0; l < 4; ++l){
    const int T = Tcur[l];
    const int Mrows = NB*T;
    const u16* Xin = (l == 0) ? Xa : ((l == 3) ? Xa : Xb);  // l0:Xa, l1:Xb, l2:Xb, l3:Xa

    const float* kl = kernels + (size_t)l*2*P*G;
    tcast_kernel<<<dim3(G/32, P/32), 256, 0, stream>>>(kl, G, P, G, Wxb);
    tcast_kernel<<<dim3(G/32, P/32), 256, 0, stream>>>(kl + (size_t)P*G, G, P, G, Whb);
    cast_kernel<<<2048, 256, 0, stream>>>(projs + (size_t)l*D*P, Pdp, (size_t)D*P);
    tcast_kernel<<<dim3(P/32, D/32), 256, 0, stream>>>(projs + (size_t)l*D*P, P, D, P, Ppd);

    // Whp^T[n][d] = sum_p Wh^T[n][p] * proj[d][p]  -> GEMM M=G, N=D, K=P
    gemm_bf16<<<dim3(D/128, G/128), 256, 0, stream>>>(G, D, P, Whb, P, BIG, 0, Pdp, Whp, D, nullptr);

    // XG = X @ Wx + bias : M=NB*T, N=G, K=P
    gemm_bf16<<<dim3(G/128, (Mrows + 127)/128), 256, 0, stream>>>(
        Mrows, G, P, Xin, P, BIG, 0, Wxb, XG, G, biases + (size_t)l*G);

    if (l == 0) h0_from_state<<<64, 256, 0, stream>>>(state + (size_t)NB*D, h0b);
    else        h0_from_h<<<64, 256, 0, stream>>>(Hb, Tcur[l-1], h0b);

    // hwh0 = h0 @ Wh : M=NB, N=G, K=P
    gemm_bf16<<<dim3(G/128, 1), 256, 0, stream>>>(NB, G, P, h0b, P, BIG, 0, Whb, hwh0, G, nullptr);

    // recurrence
    hipMemsetAsync(flags, 0, (size_t)T0*256*4, stream);
    rec_kernel<<<256, 256, 0, stream>>>(
        Whp, XG, hwh0,
        (l == 0) ? state : c_carry, c_carry, (l == 3) ? out_c : nullptr,
        U, T, flags);

    // H = U @ proj : M=NB*T, N=P, K=D
    gemm_bf16<<<dim3(P/128, (Mrows + 127)/128), 256, 0, stream>>>(
        Mrows, P, D, U, D, BIG, 0, Ppd, Hb, P, nullptr);

    if (l == 3) out_h_kernel<<<64, 256, 0, stream>>>(Hb, out_h);

    // LayerNorm: l0 -> Xb, l1 -> Xa (conv input), l2 -> Xa, l3 -> d_out (fp32)
    u16* lnout_b = (l == 0) ? Xb : ((l == 3) ? nullptr : Xa);
    ln_kernel<<<Mrows, 256, 0, stream>>>(Hb, ln_g, ln_b, lnout_b, (l == 3) ? out_main : nullptr);

    if (l == 1){
      // conv over time (VALID, width 2): A base = (r + r/511)*P
      gemm_bf16<<<dim3(P/128, (NB*T1 + 127)/128), 256, 0, stream>>>(
          NB*T1, P, 2*P, Xa, P, T1, P, Cwb, Xb, P, conv_b);
    }
  }
}